// Round 3
// baseline (546.540 us; speedup 1.0000x reference)
//
#include <hip/hip_runtime.h>
#include <hip/hip_bf16.h>
#include <cmath>

#define HH 768
#define WW 768
#define HWSZ (768*768)

typedef __attribute__((ext_vector_type(8))) short bhalf8;   // 8 bf16 in 4 VGPRs
typedef __attribute__((ext_vector_type(4))) float f32x4;
typedef __attribute__((ext_vector_type(16))) float f32x16;

__device__ inline ushort f2bf(float f) {
  __hip_bfloat16 h = __float2bfloat16(f);
  return *reinterpret_cast<ushort*>(&h);
}

// ---------------- weight transform: w1[m][c][ky][kx] fp32 -> wT[pos][m][c] bf16 (s-folded),
// ---------------- bb[m] = b1[m]*s[m] + t[m]
__global__ __launch_bounds__(256) void wxform_kernel(
    const float* __restrict__ w1, const float* __restrict__ b1,
    const float* __restrict__ s,  const float* __restrict__ t,
    ushort* __restrict__ wT, float* __restrict__ bb, int npos)
{
  int i = blockIdx.x * 256 + threadIdx.x;
  if (i < npos * 1024) {
    int pos = i >> 10, mc = i & 1023, m = mc >> 5, c = mc & 31;
    wT[i] = f2bf(w1[(m * 32 + c) * npos + pos] * s[m]);
  }
  if (i < 32) bb[i] = b1[i] * s[i] + t[i];
}

// ---------------- backbone: conv3x3 (3->32) + bias + relu, feats[b][y][x][c] bf16 ----------------
__global__ __launch_bounds__(256) void backbone_kernel(
    const float* __restrict__ x, const float* __restrict__ w,
    const float* __restrict__ bias, ushort* __restrict__ feats)
{
  int p = blockIdx.x * 256 + threadIdx.x;          // 0 .. 2*HW-1
  int bb  = p / HWSZ;
  int rem = p - bb * HWSZ;
  int y   = rem / WW;
  int xx  = rem - y * WW;
  const float* xb = x + (size_t)bb * 3 * HWSZ;

  float v[3][3][3];
  #pragma unroll
  for (int c = 0; c < 3; c++)
    #pragma unroll
    for (int dy = 0; dy < 3; dy++)
      #pragma unroll
      for (int dx = 0; dx < 3; dx++) {
        int yy = y + dy - 1, xq = xx + dx - 1;
        v[c][dy][dx] = (yy >= 0 && yy < HH && xq >= 0 && xq < WW)
                         ? xb[(size_t)c * HWSZ + yy * WW + xq] : 0.f;
      }

  union { ushort u[32]; uint4 q[4]; } pk;
  #pragma unroll
  for (int o = 0; o < 32; o++) {
    float acc = bias[o];
    #pragma unroll
    for (int c = 0; c < 3; c++)
      #pragma unroll
      for (int dy = 0; dy < 3; dy++)
        #pragma unroll
        for (int dx = 0; dx < 3; dx++)
          acc = fmaf(w[((o * 3 + c) * 3 + dy) * 3 + dx], v[c][dy][dx], acc);
    pk.u[o] = f2bf(fmaxf(acc, 0.f));
  }
  uint4* dst = (uint4*)(feats + ((size_t)bb * HWSZ + rem) * 32);
  #pragma unroll
  for (int i = 0; i < 4; i++) dst[i] = pk.q[i];
}

// ---------------- per-head epilogue: BN+relu -> LDS -> 1x1 conv -> store ----------------
template <int COUT, bool DO_TANH>
__device__ inline void head_epilogue(
    const f32x16 acc[2], const float* __restrict__ bbh,
    const float* __restrict__ w2, const float* __restrict__ b2,
    float* __restrict__ outh, float* mid,
    int wv, int qr, int qc, int kg, int by, int bx)
{
  // write mids (m = 8*rg + 4*kg + j, pixel col = q) with BN+relu
  #pragma unroll
  for (int n = 0; n < 2; n++) {
    int pix = (wv * 4 + 2 * n + qr) * 16 + qc;
    #pragma unroll
    for (int rg = 0; rg < 4; rg++) {
      int m0 = 8 * rg + 4 * kg;
      f32x4 v;
      #pragma unroll
      for (int j = 0; j < 4; j++)
        v[j] = fmaxf(acc[n][rg * 4 + j] + bbh[m0 + j], 0.f);
      *(f32x4*)(mid + pix * 36 + m0) = v;
    }
  }
  __syncthreads();

  int t = threadIdx.x;
  float mv[32];
  #pragma unroll
  for (int j2 = 0; j2 < 8; j2++)
    *(f32x4*)(mv + 4 * j2) = *(const f32x4*)(mid + t * 36 + 4 * j2);

  int oy = by * 16 + (t >> 4), ox = bx * 16 + (t & 15);
  size_t opix = (size_t)oy * WW + ox;
  #pragma unroll
  for (int oc = 0; oc < COUT; oc++) {
    float a2 = b2[oc];
    #pragma unroll
    for (int m = 0; m < 32; m++) a2 = fmaf(w2[oc * 32 + m], mv[m], a2);
    if (DO_TANH) a2 = tanhf(a2) * 3.0f;
    outh[(size_t)oc * HWSZ + opix] = a2;
  }
  __syncthreads();   // before next head overwrites mid
}

// ---------------- fused heads: score(3x3) + loc/four/ref(7x7), 32x32x16 MFMA ----------------
__global__ __launch_bounds__(256) void fused_heads_kernel(
    const ushort* __restrict__ feats,
    const ushort* __restrict__ wtS, const ushort* __restrict__ wtL,
    const ushort* __restrict__ wtF, const ushort* __restrict__ wtR,
    const float*  __restrict__ bb0,      // [4][32]: score, loc, four, ref
    const float* __restrict__ w2S, const float* __restrict__ b2S,
    const float* __restrict__ w2L, const float* __restrict__ b2L,
    const float* __restrict__ w2F, const float* __restrict__ b2F,
    const float* __restrict__ w2R, const float* __restrict__ b2R,
    float* __restrict__ out)
{
  constexpr int TW = 22, CPAD = 40;                // 22x22 halo tile, 80B/pixel slot
  __shared__ __align__(16) char smem[TW * TW * CPAD * 2];   // 38720 B (>= 256*36*4)
  ushort* tile = (ushort*)smem;

  int bx = blockIdx.x % 48;
  int by = (blockIdx.x / 48) % 48;
  int bb = blockIdx.x / 2304;
  int x0 = bx * 16 - 3, y0 = by * 16 - 3;
  const ushort* fB = feats + (size_t)bb * HWSZ * 32;

  // ---- stage halo tile (all 32 ch per pixel) ----
  for (int p = threadIdx.x; p < TW * TW; p += 256) {
    int py = p / TW, pxx = p % TW;
    int yy = y0 + py, xx = x0 + pxx;
    uint4 q0 = {0,0,0,0}, q1 = {0,0,0,0}, q2 = {0,0,0,0}, q3 = {0,0,0,0};
    if (yy >= 0 && yy < HH && xx >= 0 && xx < WW) {
      const uint4* src = (const uint4*)(fB + ((size_t)yy * WW + xx) * 32);
      q0 = src[0]; q1 = src[1]; q2 = src[2]; q3 = src[3];
    }
    uint4* dst = (uint4*)(tile + (size_t)p * CPAD);
    dst[0] = q0; dst[1] = q1; dst[2] = q2; dst[3] = q3;
  }
  __syncthreads();

  int l  = threadIdx.x & 63;
  int wv = threadIdx.x >> 6;                 // wave 0..3 -> output rows wv*4..wv*4+3
  int q  = l & 31;                           // pixel-in-group (col of MFMA)
  int kg = l >> 5;                           // k-subgroup (8 elems)
  int qr = q >> 4, qc = q & 15;              // row-in-ngrp, col

  // per-lane B base (elements): pixel (wv*4 + qr, qc), channels kg*8
  const ushort* pb = tile + ((wv * 4 + qr) * TW + qc) * CPAD + kg * 8;
  // per-lane A offset (elements): m = q, k-sub = kg*8
  const int aoff = q * 32 + kg * 8;

  f32x16 accS[2] = {};                        // score (central 3x3 taps)
  f32x16 accL[2] = {};
  f32x16 accF[2] = {};
  f32x16 accR[2] = {};

  #pragma unroll
  for (int ky = 0; ky < 7; ky++) {
    #pragma unroll
    for (int kx = 0; kx < 7; kx++) {
      const int tap = ky * 7 + kx;
      bhalf8 aL[2], aF[2], aR[2];
      #pragma unroll
      for (int kh = 0; kh < 2; kh++) {
        aL[kh] = *(const bhalf8*)(wtL + tap * 1024 + aoff + kh * 16);
        aF[kh] = *(const bhalf8*)(wtF + tap * 1024 + aoff + kh * 16);
        aR[kh] = *(const bhalf8*)(wtR + tap * 1024 + aoff + kh * 16);
      }
      bhalf8 bfr[2][2];
      #pragma unroll
      for (int n = 0; n < 2; n++)
        #pragma unroll
        for (int kh = 0; kh < 2; kh++)
          bfr[n][kh] = *(const bhalf8*)(pb + (ky * TW + kx) * CPAD + n * 2 * TW * CPAD + kh * 16);

      #pragma unroll
      for (int n = 0; n < 2; n++)
        #pragma unroll
        for (int kh = 0; kh < 2; kh++) {
          accL[n] = __builtin_amdgcn_mfma_f32_32x32x16_bf16(aL[kh], bfr[n][kh], accL[n], 0, 0, 0);
          accF[n] = __builtin_amdgcn_mfma_f32_32x32x16_bf16(aF[kh], bfr[n][kh], accF[n], 0, 0, 0);
          accR[n] = __builtin_amdgcn_mfma_f32_32x32x16_bf16(aR[kh], bfr[n][kh], accR[n], 0, 0, 0);
        }

      if (ky >= 2 && ky <= 4 && kx >= 2 && kx <= 4) {     // score 3x3 = central taps
        const int stap = (ky - 2) * 3 + (kx - 2);
        bhalf8 aS[2];
        #pragma unroll
        for (int kh = 0; kh < 2; kh++)
          aS[kh] = *(const bhalf8*)(wtS + stap * 1024 + aoff + kh * 16);
        #pragma unroll
        for (int n = 0; n < 2; n++)
          #pragma unroll
          for (int kh = 0; kh < 2; kh++)
            accS[n] = __builtin_amdgcn_mfma_f32_32x32x16_bf16(aS[kh], bfr[n][kh], accS[n], 0, 0, 0);
      }
    }
  }

  __syncthreads();                            // tile no longer needed
  float* mid = (float*)smem;

  // out chunk offsets (elements): scores 0, loc 4HW, ref 8HW, four 12HW
  head_epilogue<2,  false>(accS, bb0 +  0, w2S, b2S,
                           out + (size_t)bb * 2  * HWSZ,                     mid, wv, qr, qc, kg, by, bx);
  head_epilogue<2,  false>(accL, bb0 + 32, w2L, b2L,
                           out + (size_t)4  * HWSZ + (size_t)bb * 2  * HWSZ, mid, wv, qr, qc, kg, by, bx);
  head_epilogue<20, false>(accF, bb0 + 64, w2F, b2F,
                           out + (size_t)12 * HWSZ + (size_t)bb * 20 * HWSZ, mid, wv, qr, qc, kg, by, bx);
  head_epilogue<2,  true >(accR, bb0 + 96, w2R, b2R,
                           out + (size_t)8  * HWSZ + (size_t)bb * 2  * HWSZ, mid, wv, qr, qc, kg, by, bx);
}

extern "C" void kernel_launch(void* const* d_in, const int* in_sizes, int n_in,
                              void* d_out, int out_size, void* d_ws, size_t ws_size,
                              hipStream_t stream) {
  const float* input = (const float*)d_in[0];
  const float* bb_w  = (const float*)d_in[1];
  const float* bb_b  = (const float*)d_in[2];

  ushort* feats = (ushort*)d_ws;                             // 2*HW*32 bf16 = 75.5 MB
  char* base = (char*)d_ws;
  const size_t FEATS_BYTES = (size_t)2 * HWSZ * 32 * 2;
  const size_t WT_STRIDE   = 49 * 1024 * 2;                  // bytes per head slot
  ushort* wT0 = (ushort*)(base + FEATS_BYTES);
  float*  bb0 = (float*)(base + FEATS_BYTES + 4 * WT_STRIDE);
  (void)out_size; (void)ws_size; (void)n_in; (void)in_sizes;

  float* out = (float*)d_out;

  // weight transforms (head order: score, loc, four, ref)
  const int npos_h[4] = {9, 49, 49, 49};
  for (int h = 0; h < 4; h++) {
    const float* w1 = (const float*)d_in[3 + h * 6 + 0];
    const float* b1 = (const float*)d_in[3 + h * 6 + 1];
    const float* s  = (const float*)d_in[3 + h * 6 + 2];
    const float* t  = (const float*)d_in[3 + h * 6 + 3];
    ushort* wT = (ushort*)((char*)wT0 + h * WT_STRIDE);
    float*  bbv = bb0 + h * 32;
    int n = npos_h[h] * 1024;
    wxform_kernel<<<(n + 255) / 256, 256, 0, stream>>>(w1, b1, s, t, wT, bbv, npos_h[h]);
  }

  backbone_kernel<<<4608, 256, 0, stream>>>(input, bb_w, bb_b, feats);

  fused_heads_kernel<<<2 * 48 * 48, 256, 0, stream>>>(
      feats,
      (const ushort*)((char*)wT0 + 0 * WT_STRIDE),
      (const ushort*)((char*)wT0 + 1 * WT_STRIDE),
      (const ushort*)((char*)wT0 + 2 * WT_STRIDE),
      (const ushort*)((char*)wT0 + 3 * WT_STRIDE),
      bb0,
      (const float*)d_in[7],  (const float*)d_in[8],     // score w2,b2
      (const float*)d_in[13], (const float*)d_in[14],    // loc
      (const float*)d_in[19], (const float*)d_in[20],    // four
      (const float*)d_in[25], (const float*)d_in[26],    // ref
      out);
}

// Round 4
// 489.958 us; speedup vs baseline: 1.1155x; 1.1155x over previous
//
#include <hip/hip_runtime.h>
#include <hip/hip_bf16.h>
#include <cmath>

#define HH 768
#define WW 768
#define HWSZ (768*768)

typedef __attribute__((ext_vector_type(8))) short bhalf8;   // 8 bf16 in 4 VGPRs
typedef __attribute__((ext_vector_type(4))) float f32x4;
typedef __attribute__((ext_vector_type(16))) float f32x16;

__device__ inline ushort f2bf(float f) {
  __hip_bfloat16 h = __float2bfloat16(f);
  return *reinterpret_cast<ushort*>(&h);
}

// ---------------- weight transform: w1[m][c][ky][kx] fp32 -> wT[pos][m][c] bf16 (s-folded),
// ---------------- bb[m] = b1[m]*s[m] + t[m]
__global__ __launch_bounds__(256) void wxform_kernel(
    const float* __restrict__ w1, const float* __restrict__ b1,
    const float* __restrict__ s,  const float* __restrict__ t,
    ushort* __restrict__ wT, float* __restrict__ bb, int npos)
{
  int i = blockIdx.x * 256 + threadIdx.x;
  if (i < npos * 1024) {
    int pos = i >> 10, mc = i & 1023, m = mc >> 5, c = mc & 31;
    wT[i] = f2bf(w1[(m * 32 + c) * npos + pos] * s[m]);
  }
  if (i < 32) bb[i] = b1[i] * s[i] + t[i];
}

// ---------------- backbone: conv3x3 (3->32) + bias + relu, feats[b][y][x][c] bf16 ----------------
__global__ __launch_bounds__(256) void backbone_kernel(
    const float* __restrict__ x, const float* __restrict__ w,
    const float* __restrict__ bias, ushort* __restrict__ feats)
{
  int p = blockIdx.x * 256 + threadIdx.x;          // 0 .. 2*HW-1
  int bb  = p / HWSZ;
  int rem = p - bb * HWSZ;
  int y   = rem / WW;
  int xx  = rem - y * WW;
  const float* xb = x + (size_t)bb * 3 * HWSZ;

  float v[3][3][3];
  #pragma unroll
  for (int c = 0; c < 3; c++)
    #pragma unroll
    for (int dy = 0; dy < 3; dy++)
      #pragma unroll
      for (int dx = 0; dx < 3; dx++) {
        int yy = y + dy - 1, xq = xx + dx - 1;
        v[c][dy][dx] = (yy >= 0 && yy < HH && xq >= 0 && xq < WW)
                         ? xb[(size_t)c * HWSZ + yy * WW + xq] : 0.f;
      }

  union { ushort u[32]; uint4 q[4]; } pk;
  #pragma unroll
  for (int o = 0; o < 32; o++) {
    float acc = bias[o];
    #pragma unroll
    for (int c = 0; c < 3; c++)
      #pragma unroll
      for (int dy = 0; dy < 3; dy++)
        #pragma unroll
        for (int dx = 0; dx < 3; dx++)
          acc = fmaf(w[((o * 3 + c) * 3 + dy) * 3 + dx], v[c][dy][dx], acc);
    pk.u[o] = f2bf(fmaxf(acc, 0.f));
  }
  uint4* dst = (uint4*)(feats + ((size_t)bb * HWSZ + rem) * 32);
  #pragma unroll
  for (int i = 0; i < 4; i++) dst[i] = pk.q[i];
}

// ---------------- per-head epilogue: BN+relu -> LDS -> 1x1 conv -> store ----------------
template <int COUT, bool DO_TANH>
__device__ inline void head_epilogue(
    const f32x16 acc[2], const float* __restrict__ bbh,
    const float* __restrict__ w2, const float* __restrict__ b2,
    float* __restrict__ out_base, float* mid,
    int wv, int qr, int qc, int kg, int by, int bx, int bb)
{
  // mids: m = 8*rg + 4*kg + j, pixel col = qc, rows wv*4+2n+qr
  #pragma unroll
  for (int n = 0; n < 2; n++) {
    int pix = (wv * 4 + 2 * n + qr) * 16 + qc;
    #pragma unroll
    for (int rg = 0; rg < 4; rg++) {
      int m0 = 8 * rg + 4 * kg;
      f32x4 v;
      #pragma unroll
      for (int j = 0; j < 4; j++)
        v[j] = fmaxf(acc[n][rg * 4 + j] + bbh[m0 + j], 0.f);
      *(f32x4*)(mid + pix * 36 + m0) = v;
    }
  }
  __syncthreads();

  int t = threadIdx.x;
  float mv[32];
  #pragma unroll
  for (int j2 = 0; j2 < 8; j2++)
    *(f32x4*)(mv + 4 * j2) = *(const f32x4*)(mid + t * 36 + 4 * j2);

  int oy = by * 16 + (t >> 4), ox = bx * 16 + (t & 15);
  size_t opix = (size_t)oy * WW + ox;
  float* ob = out_base + (size_t)bb * COUT * HWSZ;
  #pragma unroll
  for (int oc = 0; oc < COUT; oc++) {
    float a2 = b2[oc];
    #pragma unroll
    for (int m = 0; m < 32; m++) a2 = fmaf(w2[oc * 32 + m], mv[m], a2);
    if (DO_TANH) a2 = tanhf(a2) * 3.0f;
    ob[(size_t)oc * HWSZ + opix] = a2;
  }
  __syncthreads();   // before next head overwrites mid
}

// ---------------- two-head fused kernel: head0 full 7x7, head1 full or central-3x3-gated ----------------
template <bool GATE1, int COUT0, bool TANH0, int COUT1, bool TANH1>
__global__ __launch_bounds__(256, 2) void heads2_kernel(
    const ushort* __restrict__ feats,
    const ushort* __restrict__ wt0, const ushort* __restrict__ wt1,
    const float*  __restrict__ bbh0, const float* __restrict__ bbh1,
    const float* __restrict__ w20, const float* __restrict__ b20,
    const float* __restrict__ w21, const float* __restrict__ b21,
    float* __restrict__ out0, float* __restrict__ out1)
{
  constexpr int TW = 22, CPAD = 40;                // 22x22 halo tile, 80B/pixel slot
  __shared__ __align__(16) char smem[TW * TW * CPAD * 2];   // 38720 B (>= 256*36*4)
  ushort* tile = (ushort*)smem;

  int bx = blockIdx.x % 48;
  int by = (blockIdx.x / 48) % 48;
  int bb = blockIdx.x / 2304;
  int x0 = bx * 16 - 3, y0 = by * 16 - 3;
  const ushort* fB = feats + (size_t)bb * HWSZ * 32;

  // ---- stage halo tile (all 32 ch per pixel) ----
  for (int p = threadIdx.x; p < TW * TW; p += 256) {
    int py = p / TW, pxx = p % TW;
    int yy = y0 + py, xx = x0 + pxx;
    uint4 q0 = {0,0,0,0}, q1 = {0,0,0,0}, q2 = {0,0,0,0}, q3 = {0,0,0,0};
    if (yy >= 0 && yy < HH && xx >= 0 && xx < WW) {
      const uint4* src = (const uint4*)(fB + ((size_t)yy * WW + xx) * 32);
      q0 = src[0]; q1 = src[1]; q2 = src[2]; q3 = src[3];
    }
    uint4* dst = (uint4*)(tile + (size_t)p * CPAD);
    dst[0] = q0; dst[1] = q1; dst[2] = q2; dst[3] = q3;
  }
  __syncthreads();

  int l  = threadIdx.x & 63;
  int wv = threadIdx.x >> 6;                 // wave 0..3 -> output rows wv*4..wv*4+3
  int q  = l & 31;                           // m row of A / pixel col of B
  int kg = l >> 5;                           // k-subgroup (8 elems)
  int qr = q >> 4, qc = q & 15;

  // per-lane B base: pixel (wv*4 + qr, qc), channels kg*8
  const ushort* pb = tile + ((wv * 4 + qr) * TW + qc) * CPAD + kg * 8;
  const int aoff = q * 32 + kg * 8;          // per-lane A offset within a tap

  f32x16 acc0[2] = {};
  f32x16 acc1[2] = {};

  #pragma unroll
  for (int ky = 0; ky < 7; ky++) {
    #pragma unroll
    for (int kx = 0; kx < 7; kx++) {
      const int tap = ky * 7 + kx;
      const bool act1 = !GATE1 || (ky >= 2 && ky <= 4 && kx >= 2 && kx <= 4);
      const int tap1 = GATE1 ? (ky - 2) * 3 + (kx - 2) : tap;

      bhalf8 a0[2], a1[2];
      #pragma unroll
      for (int kh = 0; kh < 2; kh++)
        a0[kh] = *(const bhalf8*)(wt0 + tap * 1024 + aoff + kh * 16);
      if (act1)
        #pragma unroll
        for (int kh = 0; kh < 2; kh++)
          a1[kh] = *(const bhalf8*)(wt1 + tap1 * 1024 + aoff + kh * 16);

      bhalf8 bfr[2][2];
      #pragma unroll
      for (int n = 0; n < 2; n++)
        #pragma unroll
        for (int kh = 0; kh < 2; kh++)
          bfr[n][kh] = *(const bhalf8*)(pb + (ky * TW + kx) * CPAD
                                           + n * 2 * TW * CPAD + kh * 16);

      #pragma unroll
      for (int n = 0; n < 2; n++)
        #pragma unroll
        for (int kh = 0; kh < 2; kh++) {
          acc0[n] = __builtin_amdgcn_mfma_f32_32x32x16_bf16(a0[kh], bfr[n][kh], acc0[n], 0, 0, 0);
          if (act1)
            acc1[n] = __builtin_amdgcn_mfma_f32_32x32x16_bf16(a1[kh], bfr[n][kh], acc1[n], 0, 0, 0);
        }
    }
  }

  __syncthreads();                            // tile no longer needed
  float* mid = (float*)smem;

  head_epilogue<COUT0, TANH0>(acc0, bbh0, w20, b20, out0, mid, wv, qr, qc, kg, by, bx, bb);
  head_epilogue<COUT1, TANH1>(acc1, bbh1, w21, b21, out1, mid, wv, qr, qc, kg, by, bx, bb);
}

extern "C" void kernel_launch(void* const* d_in, const int* in_sizes, int n_in,
                              void* d_out, int out_size, void* d_ws, size_t ws_size,
                              hipStream_t stream) {
  const float* input = (const float*)d_in[0];
  const float* bb_w  = (const float*)d_in[1];
  const float* bb_b  = (const float*)d_in[2];

  ushort* feats = (ushort*)d_ws;                             // 2*HW*32 bf16 = 75.5 MB
  char* base = (char*)d_ws;
  const size_t FEATS_BYTES = (size_t)2 * HWSZ * 32 * 2;
  const size_t WT_STRIDE   = 49 * 1024 * 2;                  // bytes per head slot
  ushort* wT0 = (ushort*)(base + FEATS_BYTES);
  float*  bb0 = (float*)(base + FEATS_BYTES + 4 * WT_STRIDE);
  (void)out_size; (void)ws_size; (void)n_in; (void)in_sizes;

  float* out = (float*)d_out;
  // output chunks (elements): scores @0, loc @4HW, ref @8HW, four @12HW
  float* outS = out;
  float* outL = out + (size_t)4  * HWSZ;
  float* outR = out + (size_t)8  * HWSZ;
  float* outF = out + (size_t)12 * HWSZ;

  // weight transforms (head order: score, loc, four, ref)
  const int npos_h[4] = {9, 49, 49, 49};
  for (int h = 0; h < 4; h++) {
    const float* w1 = (const float*)d_in[3 + h * 6 + 0];
    const float* b1 = (const float*)d_in[3 + h * 6 + 1];
    const float* s  = (const float*)d_in[3 + h * 6 + 2];
    const float* t  = (const float*)d_in[3 + h * 6 + 3];
    ushort* wT = (ushort*)((char*)wT0 + h * WT_STRIDE);
    float*  bbv = bb0 + h * 32;
    int n = npos_h[h] * 1024;
    wxform_kernel<<<(n + 255) / 256, 256, 0, stream>>>(w1, b1, s, t, wT, bbv, npos_h[h]);
  }

  backbone_kernel<<<4608, 256, 0, stream>>>(input, bb_w, bb_b, feats);

  const ushort* wtS = (const ushort*)((char*)wT0 + 0 * WT_STRIDE);
  const ushort* wtL = (const ushort*)((char*)wT0 + 1 * WT_STRIDE);
  const ushort* wtF = (const ushort*)((char*)wT0 + 2 * WT_STRIDE);
  const ushort* wtR = (const ushort*)((char*)wT0 + 3 * WT_STRIDE);

  // D1: loc (cout 2) + four (cout 20), both full 7x7
  heads2_kernel<false, 2, false, 20, false><<<2 * 48 * 48, 256, 0, stream>>>(
      feats, wtL, wtF, bb0 + 32, bb0 + 64,
      (const float*)d_in[13], (const float*)d_in[14],
      (const float*)d_in[19], (const float*)d_in[20],
      outL, outF);

  // D2: ref (cout 2, tanh) full 7x7 + score (cout 2) central-3x3-gated
  heads2_kernel<true, 2, true, 2, false><<<2 * 48 * 48, 256, 0, stream>>>(
      feats, wtR, wtS, bb0 + 96, bb0 + 0,
      (const float*)d_in[25], (const float*)d_in[26],
      (const float*)d_in[7],  (const float*)d_in[8],
      outR, outS);
}